// Round 17
// baseline (31.244 us; speedup 1.0000x reference)
//
#include <hip/hip_runtime.h>

// Dims
#define SS 96       // spatial
#define CC 32       // latent
#define TT 16       // time
#define BP 16       // B*P
#define MM 3072     // CC*SS; m = c*96 + e == x's natural [c][e] flat layout
#define KTOT 49152  // TT*MM: flattened k2 = t*3072 + m for GEMM2

typedef float f32x4 __attribute__((ext_vector_type(4)));
typedef short short8 __attribute__((ext_vector_type(8)));

// fp32 -> bf16 round-to-nearest-even
__device__ __forceinline__ unsigned short f2b(float f) {
    union { float f; unsigned u; } a; a.f = f;
    unsigned r = a.u + 0x7FFFu + ((a.u >> 16) & 1u);
    return (unsigned short)(r >> 16);
}

// Fragment-linear layouts (lane l consumes buf[tile][l][8] as one short8):
//  Qbf[(mtile*3+kt)*512 + l*8 + j] : A of GEMM1. row m = mtile*16+(l&15),
//                                    k v = kt*32+(l>>4)*8+j
//  wabf[(X*3+kt)*512 + l*8 + j]   : B of GEMM1. col t = l&15, same v map
//  xbf[(tile*64+l)*8 + j]         : B of GEMM2. col b = l&15,
//                                    k2 = tile*32+(l>>4)*8+j, tile = t*96+mc

// ---------------------------------------------------------------------------
// K1: prep-all (grid 576) — everything that depends only on inputs:
//   [0,96):    Kt[X][m=c*96+e] = K[X][e*32+c]            (fp32, epilogue)
//   [96,192):  Qbf from Q (one e-slab per block)
//   [192,288): wabf[X] = bf16(w[v]*Aoo[X][v*16+t])       (frag-linear)
//   [288,384): xbf = bf16(x), frag-linear
//   [384,576): q[bp][X][c] = sum_e V[X,e,c]*x[bp,T-1,c,e]
//   block 0 additionally zeroes y (atomic-accumulated in K2; replay-safe).
__global__ __launch_bounds__(256) void k_prep(
    const float* __restrict__ x, const float* __restrict__ Q,
    const float* __restrict__ K, const float* __restrict__ V,
    const float* __restrict__ Aoo, const float* __restrict__ w,
    float* __restrict__ Kt, unsigned short* __restrict__ Qbf,
    unsigned short* __restrict__ wabf, unsigned short* __restrict__ xbf,
    float* __restrict__ q, float* __restrict__ y)
{
    __shared__ __align__(16) union {
        float sb[SS * 33];
        unsigned short cvt[16][520];
    } sm;
    const int bid = blockIdx.x, tid = threadIdx.x;
    if (bid == 0) { y[tid] = 0.f; y[tid + 256] = 0.f; }
    if (bid < 96) {
        const int X = bid;
        const float* src = K + (size_t)X * MM;
        float* dst = Kt + (size_t)X * MM;
        for (int i = tid; i < MM; i += 256) {
            int e = i >> 5, c = i & 31;
            sm.sb[e * 33 + c] = src[i];
        }
        __syncthreads();
        for (int j = tid; j < MM; j += 256) {
            int c = j / SS, e = j - c * SS;
            dst[j] = sm.sb[e * 33 + c];
        }
    } else if (bid < 192) {
        const int e = bid - 96;
        for (int i = tid; i < MM; i += 256) {          // i = v*32 + c
            int v = i >> 5, c = i & 31;
            sm.sb[v * 33 + c] = Q[(size_t)v * MM + e * 32 + c];
        }
        __syncthreads();
        for (int g = tid; g < 384; g += 256) {         // g = c*12 + vg
            const int c = g / 12, vg = g - c * 12;
            const int mtile = c * 6 + (e >> 4);
            const int kt = vg >> 2;
            const int lane = ((vg & 3) << 4) | (e & 15);
            short8 o;
#pragma unroll
            for (int j = 0; j < 8; ++j)
                o[j] = (short)f2b(sm.sb[(vg * 8 + j) * 33 + c]);
            *(short8*)(Qbf + (size_t)(mtile * 3 + kt) * 512 + lane * 8) = o;
        }
    } else if (bid < 288) {
        const int X = bid - 192;
        for (int i = tid; i < SS * TT; i += 256)       // i = v*16 + t
            sm.sb[i] = Aoo[(size_t)X * (SS * TT) + i];
        if (tid < SS) sm.sb[1600 + tid] = w[tid];
        __syncthreads();
        if (tid < 192) {                               // tid = kt*64 + l
            const int kt = tid >> 6, l = tid & 63;
            const int t = l & 15, v0 = kt * 32 + ((l >> 4) << 3);
            short8 o;
#pragma unroll
            for (int j = 0; j < 8; ++j)
                o[j] = (short)f2b(sm.sb[1600 + v0 + j] * sm.sb[(v0 + j) * 16 + t]);
            *(short8*)(wabf + (size_t)(X * 3 + kt) * 512 + l * 8) = o;
        }
    } else if (bid < 384) {
        // ---- xbf convert: k2 range [cb*512, +512) for all 16 b
        const int cb = bid - 288;
        const int b = tid >> 4, cb32 = (tid & 15) * 32;
        const float* xp = x + (size_t)b * KTOT + cb * 512 + cb32;
#pragma unroll
        for (int k = 0; k < 32; k += 4) {
            float4 v4 = *(const float4*)(xp + k);
            sm.cvt[b][cb32 + k + 0] = f2b(v4.x);
            sm.cvt[b][cb32 + k + 1] = f2b(v4.y);
            sm.cvt[b][cb32 + k + 2] = f2b(v4.z);
            sm.cvt[b][cb32 + k + 3] = f2b(v4.w);
        }
        __syncthreads();
#pragma unroll
        for (int it = 0; it < 4; ++it) {
            const int i = tid + it * 256;              // i = kt2*64 + l
            const int kt2 = i >> 6, l = i & 63;
            short8 o = *(const short8*)(&sm.cvt[l & 15][kt2 * 32 + ((l >> 4) << 3)]);
            *(short8*)(xbf + ((size_t)(cb * 16 + kt2) * 64 + l) * 8) = o;
        }
    } else {
        // ---- q path: one block per (bp, xc)
        const int qb = bid - 384;
        const int bp = qb / 12, xc = qb - (qb / 12) * 12;
        const float* xs = x + (size_t)bp * (TT * MM) + (TT - 1) * MM;  // [c][e]
        for (int i = tid; i < MM; i += 256) {
            int c = i / SS, e = i - (i / SS) * SS;
            sm.sb[e * 33 + c] = xs[i];
        }
        __syncthreads();
        const int c = tid & 31, grp = tid >> 5;
        const int X = xc * 8 + grp;
        const float* Vp = V + (size_t)X * MM + c;
        float acc = 0.f;
#pragma unroll 8
        for (int e = 0; e < SS; ++e)
            acc = fmaf(Vp[e * CC], sm.sb[e * 33 + c], acc);
        q[((size_t)bp * SS + X) * CC + c] = acc;
    }
}

// ---------------------------------------------------------------------------
// K2: fused GEMM1 -> LDS -> GEMM2 -> y-fold (grid 576 = 96 mc x 6 xt,
// XCD-chunked). W2 tile lives only in LDS (R16, verified). New tail: instead
// of storing Gp split-K partials for a 3rd kernel, each block folds its
// Gloc[16X x 16b] into y via one atomicAdd per output (R14 pattern).
// fp32 ordering jitter ~ulp << 4.5e-5 threshold.
__global__ __launch_bounds__(256) void k_fused(
    const unsigned short* __restrict__ Qbf, const unsigned short* __restrict__ wabf,
    const float* __restrict__ Kt, const unsigned short* __restrict__ xbf,
    const float* __restrict__ q, float* __restrict__ y)
{
    __shared__ __align__(16) unsigned short w2s[16 * 516];  // 16 k2-tiles + pad
    __shared__ float red[1024];
    __shared__ float Gloc[256];
    const int flat = blockIdx.x;
    const int bid = (flat & 7) * 72 + (flat >> 3);  // XCD chunk (576 = 8*72)
    const int mc = bid / 6, xt = bid - (bid / 6) * 6;
    const int tid = threadIdx.x;
    const int lane = tid & 63, wv = tid >> 6;
    const int l15 = lane & 15, lg = lane >> 4;

    // GEMM1 A-frags for mtiles {2mc, 2mc+1} — shared by all 16 X
    short8 af[2][3];
#pragma unroll
    for (int mtl = 0; mtl < 2; ++mtl)
#pragma unroll
        for (int kt = 0; kt < 3; ++kt)
            af[mtl][kt] = *(const short8*)(
                Qbf + (size_t)((mc * 2 + mtl) * 3 + kt) * 512 + lane * 8);

#pragma unroll
    for (int xi = 0; xi < 4; ++xi) {
        const int Xl = wv * 4 + xi;                 // wave owns 4 X rows
        const int X = xt * 16 + Xl;
        const unsigned short* bw = wabf + (size_t)X * 3 * 512 + lane * 8;
        const short8 b0 = *(const short8*)(bw);
        const short8 b1 = *(const short8*)(bw + 512);
        const short8 b2 = *(const short8*)(bw + 1024);
#pragma unroll
        for (int mtl = 0; mtl < 2; ++mtl) {
            f32x4 acc = {0.f, 0.f, 0.f, 0.f};
            acc = __builtin_amdgcn_mfma_f32_16x16x32_bf16(af[mtl][0], b0, acc, 0, 0, 0);
            acc = __builtin_amdgcn_mfma_f32_16x16x32_bf16(af[mtl][1], b1, acc, 0, 0, 0);
            acc = __builtin_amdgcn_mfma_f32_16x16x32_bf16(af[mtl][2], b2, acc, 0, 0, 0);
            // C: col(l15)=t, rows m_local = mtl*16 + lg*4 + r
            const int mloc = mtl * 16 + lg * 4;
            const f32x4 kt4 = *(const f32x4*)(Kt + (size_t)X * MM + mc * 32 + mloc);
            ushort4 o;
            o.x = f2b(acc[0] * kt4[0]);
            o.y = f2b(acc[1] * kt4[1]);
            o.z = f2b(acc[2] * kt4[2]);
            o.w = f2b(acc[3] * kt4[3]);
            // scatter to GEMM2-A frag order: tile t=l15, lane (k>>3)*16+Xl, elem k&7
            *(ushort4*)(&w2s[l15 * 516 + ((mloc >> 3) * 16 + Xl) * 8 + (lg & 1) * 4]) = o;
        }
    }
    __syncthreads();

    // GEMM2: wave wv handles t = wv*4..+4; A from LDS, B from global xbf
    f32x4 acc2 = {0.f, 0.f, 0.f, 0.f};
#pragma unroll
    for (int ts = 0; ts < 4; ++ts) {
        const int t = wv * 4 + ts;
        const short8 a2 = *(const short8*)(&w2s[t * 516 + lane * 8]);
        const short8 b2f = *(const short8*)(xbf + ((size_t)(t * SS + mc) * 64 + lane) * 8);
        acc2 = __builtin_amdgcn_mfma_f32_16x16x32_bf16(a2, b2f, acc2, 0, 0, 0);
    }
#pragma unroll
    for (int r = 0; r < 4; ++r)
        red[(wv * 64 + lane) * 4 + r] = acc2[r];
    __syncthreads();
    {   // C layout: col(l&15)=b, row((l>>4)*4+r)=Xl  (verified R11-R16)
        const int Xl = tid >> 4, b = tid & 15;
        const int l = ((Xl >> 2) << 4) | b, r = Xl & 3;
        Gloc[tid] = red[(0 * 64 + l) * 4 + r] + red[(1 * 64 + l) * 4 + r] +
                    red[(2 * 64 + l) * 4 + r] + red[(3 * 64 + l) * 4 + r];
    }
    __syncthreads();

    // y-fold: y[bp,c] += sum_Xl q[bp, xt*16+Xl, c] * Gloc[Xl*16+bp]
#pragma unroll
    for (int pass = 0; pass < 2; ++pass) {
        const int out = tid + pass * 256;
        const int bp = out >> 5, c = out & 31;
        const float* qp = q + ((size_t)bp * SS + xt * 16) * CC + c;
        float a = 0.f;
#pragma unroll
        for (int Xl = 0; Xl < 16; ++Xl)
            a = fmaf(qp[(size_t)Xl * CC], Gloc[Xl * BP + bp], a);
        atomicAdd(&y[out], a);
    }
}

// ---------------------------------------------------------------------------
extern "C" void kernel_launch(void* const* d_in, const int* in_sizes, int n_in,
                              void* d_out, int out_size, void* d_ws, size_t ws_size,
                              hipStream_t stream) {
    const float* x   = (const float*)d_in[0];
    const float* Q   = (const float*)d_in[1];
    const float* K   = (const float*)d_in[2];
    const float* V   = (const float*)d_in[3];
    const float* Aoo = (const float*)d_in[4];
    const float* w   = (const float*)d_in[5];

    char* wsb = (char*)d_ws;                        // 16B-aligned offsets
    float*          Kt   = (float*)(wsb);                     // 1,179,648 B
    float*          qb_  = (float*)(wsb + 1179648);           //   196,608 B
    unsigned short* Qbf  = (unsigned short*)(wsb + 1376256);  //   589,824 B
    unsigned short* wabf = (unsigned short*)(wsb + 1966080);  //   294,912 B
    unsigned short* xbf  = (unsigned short*)(wsb + 2260992);  // 1,572,864 B
    float* y = (float*)d_out;                       // total ws: ~3.8 MB

    k_prep<<<dim3(576), 256, 0, stream>>>(x, Q, K, V, Aoo, w, Kt, Qbf, wabf,
                                          xbf, qb_, y);
    k_fused<<<dim3(576), 256, 0, stream>>>(Qbf, wabf, Kt, xbf, qb_, y);
}

// Round 18
// 20.371 us; speedup vs baseline: 1.5338x; 1.5338x over previous
//
#include <hip/hip_runtime.h>

// Dims
#define SS 96       // spatial
#define CC 32       // latent
#define TT 16       // time
#define BP 16       // B*P
#define MM 3072     // SS*CC; m = e*32 + c == Q/K's natural flat layout
#define KTOT 49152  // TT*MM: flattened k2 = t*3072 + m for GEMM2
#define NKB 96      // split-K partials (one per mc = e chunk of 32 m)

typedef float f32x4 __attribute__((ext_vector_type(4)));
typedef short short8 __attribute__((ext_vector_type(8)));

// fp32 -> bf16 round-to-nearest-even
__device__ __forceinline__ unsigned short f2b(float f) {
    union { float f; unsigned u; } a; a.f = f;
    unsigned r = a.u + 0x7FFFu + ((a.u >> 16) & 1u);
    return (unsigned short)(r >> 16);
}

// Fragment-linear layouts (lane l consumes buf[tile][l][8] as one short8):
//  Qbf[(mtile*3+kt)*512 + l*8 + j] : A of GEMM1. row m = mtile*16+(l&15),
//                                    k v = kt*32+(l>>4)*8+j
//  wabf[(X*3+kt)*512 + l*8 + j]   : B of GEMM1. col t = l&15, same v map
//  xbf[(tile*64+l)*8 + j]         : B of GEMM2. col b = l&15,
//                                    tile = t*96+e, k2-local c = (l>>4)*8+j
// With m = e*32+c, an mc chunk of 32 m == one e value; k2-local == c on both
// GEMM2 operands (A scatter uses mloc = c as well) — orders agree.

// ---------------------------------------------------------------------------
// K1: prep (grid 288):
//   [0,96):    Qbf from Q — block = one e-slab (rows m = e*32+c, all c,v)
//   [96,192):  wabf[X] = bf16(w[v]*Aoo[X][v*16+t])       (frag-linear)
//   [192,288): xbf = bf16(x) transposed to m-order — block = (t, 16-e slab)
__global__ __launch_bounds__(256) void k_prep(
    const float* __restrict__ x, const float* __restrict__ Q,
    const float* __restrict__ Aoo, const float* __restrict__ w,
    unsigned short* __restrict__ Qbf, unsigned short* __restrict__ wabf,
    unsigned short* __restrict__ xbf)
{
    __shared__ __align__(16) union {
        float sb[SS * 33];
        unsigned short cv[16][16][40];   // [b][e_local][c], row 80B (16B mult)
    } sm;
    const int bid = blockIdx.x, tid = threadIdx.x;
    if (bid < 96) {
        const int e = bid;
        for (int i = tid; i < MM; i += 256) {          // i = v*32 + c
            int v = i >> 5, c = i & 31;
            sm.sb[v * 33 + c] = Q[(size_t)v * MM + e * 32 + c];
        }
        __syncthreads();
        for (int g = tid; g < 384; g += 256) {         // g = c*12 + vg
            const int c = g / 12, vg = g - c * 12;
            const int mtile = e * 2 + (c >> 4);        // m = e*32+c
            const int kt = vg >> 2;
            const int lane = ((vg & 3) << 4) | (c & 15);
            short8 o;
#pragma unroll
            for (int j = 0; j < 8; ++j)
                o[j] = (short)f2b(sm.sb[(kt * 32 + (vg & 3) * 8 + j) * 33 + c]);
            *(short8*)(Qbf + (size_t)(mtile * 3 + kt) * 512 + lane * 8) = o;
        }
    } else if (bid < 192) {
        const int X = bid - 96;
        for (int i = tid; i < SS * TT; i += 256)       // i = v*16 + t
            sm.sb[i] = Aoo[(size_t)X * (SS * TT) + i];
        if (tid < SS) sm.sb[1600 + tid] = w[tid];
        __syncthreads();
        if (tid < 192) {                               // tid = kt*64 + l
            const int kt = tid >> 6, l = tid & 63;
            const int t = l & 15, v0 = kt * 32 + ((l >> 4) << 3);
            short8 o;
#pragma unroll
            for (int j = 0; j < 8; ++j)
                o[j] = (short)f2b(sm.sb[1600 + v0 + j] * sm.sb[(v0 + j) * 16 + t]);
            *(short8*)(wabf + (size_t)(X * 3 + kt) * 512 + l * 8) = o;
        }
    } else {
        // ---- xbf transpose+convert: block = (t, e-range [e0, e0+16))
        const int cb = bid - 192;
        const int t = cb / 6, eg = cb - (cb / 6) * 6;
        const int e0 = eg * 16;
#pragma unroll
        for (int it = 0; it < 2; ++it) {
            const int p = it * 256 + tid;              // p = b*32 + c
            const int b = p >> 5, c = p & 31;
            const float* xp = x + (size_t)b * KTOT + (size_t)t * MM + c * SS + e0;
#pragma unroll
            for (int k = 0; k < 16; k += 4) {
                float4 v4 = *(const float4*)(xp + k);
                sm.cv[b][k + 0][c] = f2b(v4.x);
                sm.cv[b][k + 1][c] = f2b(v4.y);
                sm.cv[b][k + 2][c] = f2b(v4.z);
                sm.cv[b][k + 3][c] = f2b(v4.w);
            }
        }
        __syncthreads();
#pragma unroll
        for (int it = 0; it < 4; ++it) {
            const int slot = it * 256 + tid;           // slot = tileL*64 + l
            const int tileL = slot >> 6, l = slot & 63;
            short8 o = *(const short8*)(&sm.cv[l & 15][tileL][(l >> 4) * 8]);
            *(short8*)(xbf + ((size_t)(t * SS + e0 + tileL) * 64 + l) * 8) = o;
        }
    }
}

// ---------------------------------------------------------------------------
// K2: fused GEMM1 -> LDS -> GEMM2 (blocks [0,576), XCD-chunked) + q GEMV
// (blocks [576,768) — moved here from prep: depends only on inputs, feeds
// only k_final). W2 tile lives in LDS only (R16, verified). K read directly
// (its natural layout IS m-order now — Kt buffer deleted).
// Gp[(X*16+b)*96 + mc] plain store; NO atomics (R17 lesson: 576 adders on
// 512 addresses cost +11us — split-K partials + consumer kernel instead).
__global__ __launch_bounds__(256) void k_fused(
    const unsigned short* __restrict__ Qbf, const unsigned short* __restrict__ wabf,
    const float* __restrict__ K, const unsigned short* __restrict__ xbf,
    const float* __restrict__ x, const float* __restrict__ V,
    float* __restrict__ Gp, float* __restrict__ q)
{
    __shared__ __align__(16) union {
        struct {
            unsigned short w2s[16 * 516];   // 16 k2-tiles + pad (conflict-free)
            float red[1024];
            float Gloc[256];
        } g;
        float qsm[SS * 33];
    } sm;
    const int flat = blockIdx.x;
    const int tid = threadIdx.x;

    if (flat >= 576) {
        // ---- q path: one block per (bp, xc)
        const int qb = flat - 576;
        const int bp = qb / 12, xc = qb - (qb / 12) * 12;
        const float* xs = x + (size_t)bp * (TT * MM) + (TT - 1) * MM;  // [c][e]
        for (int i = tid; i < MM; i += 256) {
            int c = i / SS, e = i - (i / SS) * SS;
            sm.qsm[e * 33 + c] = xs[i];
        }
        __syncthreads();
        const int c = tid & 31, grp = tid >> 5;
        const int X = xc * 8 + grp;
        const float* Vp = V + (size_t)X * MM + c;
        float acc = 0.f;
#pragma unroll 8
        for (int e = 0; e < SS; ++e)
            acc = fmaf(Vp[e * CC], sm.qsm[e * 33 + c], acc);
        q[((size_t)bp * SS + X) * CC + c] = acc;
        return;
    }
    const int bid = (flat & 7) * 72 + (flat >> 3);  // XCD chunk (576 = 8*72)
    const int mc = bid / 6, xt = bid - (bid / 6) * 6;
    const int lane = tid & 63, wv = tid >> 6;
    const int l15 = lane & 15, lg = lane >> 4;

    // GEMM1 A-frags for mtiles {2mc, 2mc+1} — shared by all 16 X
    short8 af[2][3];
#pragma unroll
    for (int mtl = 0; mtl < 2; ++mtl)
#pragma unroll
        for (int kt = 0; kt < 3; ++kt)
            af[mtl][kt] = *(const short8*)(
                Qbf + (size_t)((mc * 2 + mtl) * 3 + kt) * 512 + lane * 8);

#pragma unroll
    for (int xi = 0; xi < 4; ++xi) {
        const int Xl = wv * 4 + xi;                 // wave owns 4 X rows
        const int X = xt * 16 + Xl;
        const unsigned short* bw = wabf + (size_t)X * 3 * 512 + lane * 8;
        const short8 b0 = *(const short8*)(bw);
        const short8 b1 = *(const short8*)(bw + 512);
        const short8 b2 = *(const short8*)(bw + 1024);
#pragma unroll
        for (int mtl = 0; mtl < 2; ++mtl) {
            f32x4 acc = {0.f, 0.f, 0.f, 0.f};
            acc = __builtin_amdgcn_mfma_f32_16x16x32_bf16(af[mtl][0], b0, acc, 0, 0, 0);
            acc = __builtin_amdgcn_mfma_f32_16x16x32_bf16(af[mtl][1], b1, acc, 0, 0, 0);
            acc = __builtin_amdgcn_mfma_f32_16x16x32_bf16(af[mtl][2], b2, acc, 0, 0, 0);
            // C: col(l15)=t, rows mloc = mtl*16 + lg*4 + r; m = mc*32 + mloc
            const int mloc = mtl * 16 + lg * 4;
            const f32x4 kt4 = *(const f32x4*)(K + (size_t)X * MM + mc * 32 + mloc);
            ushort4 o;
            o.x = f2b(acc[0] * kt4[0]);
            o.y = f2b(acc[1] * kt4[1]);
            o.z = f2b(acc[2] * kt4[2]);
            o.w = f2b(acc[3] * kt4[3]);
            // scatter to GEMM2-A frag order: tile t=l15, lane (mloc>>3)*16+Xl
            *(ushort4*)(&sm.g.w2s[l15 * 516 + ((mloc >> 3) * 16 + Xl) * 8 + (lg & 1) * 4]) = o;
        }
    }
    __syncthreads();

    // GEMM2: wave wv handles t = wv*4..+4; A from LDS, B from global xbf
    f32x4 acc2 = {0.f, 0.f, 0.f, 0.f};
#pragma unroll
    for (int ts = 0; ts < 4; ++ts) {
        const int t = wv * 4 + ts;
        const short8 a2 = *(const short8*)(&sm.g.w2s[t * 516 + lane * 8]);
        const short8 b2f = *(const short8*)(xbf + ((size_t)(t * SS + mc) * 64 + lane) * 8);
        acc2 = __builtin_amdgcn_mfma_f32_16x16x32_bf16(a2, b2f, acc2, 0, 0, 0);
    }
#pragma unroll
    for (int r = 0; r < 4; ++r)
        sm.g.red[(wv * 64 + lane) * 4 + r] = acc2[r];
    __syncthreads();
    {   // C layout: col(l&15)=b, row((l>>4)*4+r)=Xl  (verified R11-R17)
        const int Xl = tid >> 4, b = tid & 15;
        const int l = ((Xl >> 2) << 4) | b, r = Xl & 3;
        float s = sm.g.red[(0 * 64 + l) * 4 + r] + sm.g.red[(1 * 64 + l) * 4 + r] +
                  sm.g.red[(2 * 64 + l) * 4 + r] + sm.g.red[(3 * 64 + l) * 4 + r];
        Gp[(size_t)((xt * 16 + Xl) * BP + b) * NKB + mc] = s;
    }
}

// ---------------------------------------------------------------------------
// K3: final (grid 16 = bp): G[X] = sum_mc Gp[(X*16+bp)*96+mc] (contiguous,
// fixed order), y[bp,c] = sum_X q[bp,X,c]*G[X]. Deterministic plain stores.
__global__ __launch_bounds__(256) void k_final(
    const float* __restrict__ Gp, const float* __restrict__ q,
    float* __restrict__ y)
{
    const int bp = blockIdx.x, tid = threadIdx.x;
    __shared__ float Gh[SS][2];
    __shared__ float G[SS];
    __shared__ float red2[8 * CC];
    if (tid < 192) {
        const int X = tid >> 1, h = tid & 1;
        const float* p = Gp + (size_t)(X * BP + bp) * NKB + h * 48;
        float s = 0.f;
#pragma unroll
        for (int j = 0; j < 12; ++j) {
            f32x4 v4 = *(const f32x4*)(p + j * 4);
            s += v4[0] + v4[1] + v4[2] + v4[3];
        }
        Gh[X][h] = s;
    }
    __syncthreads();
    if (tid < SS) G[tid] = Gh[tid][0] + Gh[tid][1];
    __syncthreads();

    const int c = tid & 31, grp = tid >> 5;
    float acc = 0.f;
#pragma unroll
    for (int k = 0; k < 12; ++k) {
        const int X = grp * 12 + k;
        acc = fmaf(q[((size_t)bp * SS + X) * CC + c], G[X], acc);
    }
    red2[grp * CC + c] = acc;
    __syncthreads();
    if (tid < CC) {
        float s = 0.f;
#pragma unroll
        for (int g8 = 0; g8 < 8; ++g8) s += red2[g8 * CC + tid];
        y[bp * CC + tid] = s;
    }
}

// ---------------------------------------------------------------------------
extern "C" void kernel_launch(void* const* d_in, const int* in_sizes, int n_in,
                              void* d_out, int out_size, void* d_ws, size_t ws_size,
                              hipStream_t stream) {
    const float* x   = (const float*)d_in[0];
    const float* Q   = (const float*)d_in[1];
    const float* K   = (const float*)d_in[2];
    const float* V   = (const float*)d_in[3];
    const float* Aoo = (const float*)d_in[4];
    const float* w   = (const float*)d_in[5];

    char* wsb = (char*)d_ws;                        // 16B-aligned offsets
    float*          Gp   = (float*)(wsb);                     //   589,824 B
    float*          qb_  = (float*)(wsb + 589824);            //   196,608 B
    unsigned short* Qbf  = (unsigned short*)(wsb + 786432);   //   589,824 B
    unsigned short* wabf = (unsigned short*)(wsb + 1376256);  //   294,912 B
    unsigned short* xbf  = (unsigned short*)(wsb + 1671168);  // 1,572,864 B
    float* y = (float*)d_out;                       // total ws: ~3.2 MB

    k_prep<<<dim3(288), 256, 0, stream>>>(x, Q, Aoo, w, Qbf, wabf, xbf);
    k_fused<<<dim3(768), 256, 0, stream>>>(Qbf, wabf, K, xbf, x, V, Gp, qb_);
    k_final<<<dim3(BP), 256, 0, stream>>>(Gp, qb_, y);
}